// Round 2
// baseline (8884.420 us; speedup 1.0000x reference)
//
#include <hip/hip_runtime.h>

typedef __attribute__((ext_vector_type(8))) short bf16x8;
typedef __attribute__((ext_vector_type(4))) float f32x4;
typedef unsigned short u16;
typedef unsigned int u32;

#define AS1 __attribute__((address_space(1)))
#define AS3 __attribute__((address_space(3)))

// ---------- helpers ----------
__device__ __forceinline__ float b2f(u16 u) {
  union { u32 i; float f; } v; v.i = ((u32)u) << 16; return v.f;
}
__device__ __forceinline__ u16 f2b(float f) {
  union { float f; u32 i; } v; v.f = f;
  u32 u = v.i;
  return (u16)((u + 0x7FFFu + ((u >> 16) & 1u)) >> 16);   // RNE
}
__device__ __forceinline__ void gload_lds16(const void* g, void* lds) {
  __builtin_amdgcn_global_load_lds((const AS1 u32*)g, (AS3 u32*)lds, 16, 0, 0);
}
__device__ __forceinline__ float sigm(float x) { return 1.f / (1.f + __expf(-x)); }
__device__ __forceinline__ float tanh_fast(float x) { return 1.f - 2.f / (__expf(2.f * x) + 1.f); }

// ---------- 1. f32 -> bf16 convert (8 elems/thread) ----------
__global__ void k_cvt_bf16(const float* __restrict__ src, u16* __restrict__ dst, int n8) {
  int i = blockIdx.x * 256 + threadIdx.x;
  if (i < n8) {
    const float4* s = (const float4*)src + (size_t)i * 2;
    float4 a = s[0], b = s[1];
    u16 o[8] = { f2b(a.x), f2b(a.y), f2b(a.z), f2b(a.w), f2b(b.x), f2b(b.y), f2b(b.z), f2b(b.w) };
    *(uint4*)(dst + (size_t)i * 8) = *(uint4*)o;
  }
}

// ---------- 2. embedding lookup -> bf16 [32768][512] (row = t*64+b) ----------
__global__ void k_embed(const int* __restrict__ tokens, const float* __restrict__ embed,
                        u16* __restrict__ out) {
  int row = blockIdx.x * 4 + (threadIdx.x >> 6);
  int e0  = (threadIdx.x & 63) * 8;
  int tok = tokens[row];
  const float4* s = (const float4*)(embed + (size_t)tok * 512 + e0);
  float4 a = s[0], b = s[1];
  u16 o[8] = { f2b(a.x), f2b(a.y), f2b(a.z), f2b(a.w), f2b(b.x), f2b(b.y), f2b(b.z), f2b(b.w) };
  *(uint4*)(out + (size_t)row * 512 + e0) = *(uint4*)o;
}

// ---------- 3. pack w_tag [16][1024] f32 -> B-frag stream [32 kc][64 lane][8] bf16 ----------
__global__ void k_pack_wtag(const float* __restrict__ wtag, u16* __restrict__ out) {
  for (int s = threadIdx.x; s < 2048; s += 256) {
    int kc = s >> 6, lane = s & 63;
    int col = lane & 15, k0 = kc * 32 + (lane >> 4) * 8;
    const float4* src = (const float4*)(wtag + col * 1024 + k0);
    float4 a = src[0], b = src[1];
    u16 o[8] = { f2b(a.x), f2b(a.y), f2b(a.z), f2b(a.w), f2b(b.x), f2b(b.y), f2b(b.z), f2b(b.w) };
    *(uint4*)(out + (size_t)s * 8) = *(uint4*)o;
  }
}

// ---------- 4. persistent bi-LSTM recurrence (fused ih + hh) ----------
// 64 WGs: d = wg>>5 (0 fwd, 1 bwd), cg = wg&31 owns h-cols [cg*16, cg*16+16).
// Wave q = gate q (i,f,g,o). w_ih and w_hh fragments live in VGPRs (128 regs).
// Per step: acc = bias; acc += x(t)@W_ih^T + h(t-1)@W_hh^T (MFMA, K=512 each);
// gate exchange via LDS; activations; h broadcast via global ping-pong + barrier.
__launch_bounds__(256, 1)
__global__ void k_lstm(const u16* __restrict__ whh,      // [2][2048][512] bf16 rm
                       const u16* __restrict__ wih,      // [2][2048][512] bf16 rm
                       const float* __restrict__ bias_f, const float* __restrict__ bias_b,
                       const u16* __restrict__ embeds,   // [512*64][512] bf16 rm
                       u16* __restrict__ hbuf,           // [2][2][64][512] bf16 chunk-swizzled
                       u16* __restrict__ h_all,          // [512][64][1024] bf16 rm
                       int* __restrict__ bar) {
  __shared__ u16 h_lds[64 * 512];          // 64 KB (low 16 KB reused for gate exchange)
  __shared__ u16 x_lds[64 * 512];          // 64 KB
  float* gex = (float*)h_lds;              // [4][64][16] f32
  int wg = blockIdx.x;
  int d = wg >> 5, cg = wg & 31;
  int tid = threadIdx.x, q = tid >> 6, l = tid & 63;

  // load weight B-fragments into registers (once)
  bf16x8 wreg[16], xreg[16];
  {
    size_t roff = ((size_t)d * 2048 + q * 512 + cg * 16 + (l & 15)) * 512 + (l >> 4) * 8;
    const u16* wb = whh + roff;
    const u16* xb = wih + roff;
    #pragma unroll
    for (int kk = 0; kk < 16; kk++) {
      wreg[kk] = *(const bf16x8*)(wb + kk * 32);
      xreg[kk] = *(const bf16x8*)(xb + kk * 32);
    }
  }
  float bias = (d ? bias_b : bias_f)[q * 512 + cg * 16 + (l & 15)];

  // zero h(-1)
  {
    uint4 z = {0, 0, 0, 0};
    for (int i = tid; i < 4096; i += 256) ((uint4*)h_lds)[i] = z;
  }
  float c[4] = {0.f, 0.f, 0.f, 0.f};

  // pre-stage x(tau0): pre-swizzled global source -> linear LDS
  {
    int tau0 = d ? 511 : 0;
    #pragma unroll
    for (int i = 0; i < 16; i++) {
      int r = q * 16 + i;
      const u16* src = embeds + ((size_t)(tau0 * 64 + r)) * 512 + (size_t)(l ^ (r & 7)) * 8;
      gload_lds16(src, x_lds + r * 512);
    }
  }
  __syncthreads();

  for (int t = 0; t < 512; t++) {
    int tau = d ? (511 - t) : t;
    f32x4 acc[4];
    #pragma unroll
    for (int m = 0; m < 4; m++) { acc[m].x = bias; acc[m].y = bias; acc[m].z = bias; acc[m].w = bias; }
    // gates = bias + x@W_ih^T + h@W_hh^T
    #pragma unroll
    for (int kk = 0; kk < 16; kk++) {
      bf16x8 ax[4], ah[4];
      #pragma unroll
      for (int m = 0; m < 4; m++) {
        int row = m * 16 + (l & 15);
        int ch = (((kk * 4 + (l >> 4)) ^ (row & 7)) * 8);
        ax[m] = *(const bf16x8*)(x_lds + row * 512 + ch);
        ah[m] = *(const bf16x8*)(h_lds + row * 512 + ch);
      }
      #pragma unroll
      for (int m = 0; m < 4; m++)
        acc[m] = __builtin_amdgcn_mfma_f32_16x16x32_bf16(ax[m], xreg[kk], acc[m], 0, 0, 0);
      #pragma unroll
      for (int m = 0; m < 4; m++)
        acc[m] = __builtin_amdgcn_mfma_f32_16x16x32_bf16(ah[m], wreg[kk], acc[m], 0, 0, 0);
    }
    __syncthreads();                      // everyone done reading x_lds/h_lds
    // gate exchange through LDS (C/D layout: col=l&15, row=(l>>4)*4+reg)
    #pragma unroll
    for (int m = 0; m < 4; m++) {
      int r0 = m * 16 + (l >> 4) * 4;
      float* gq = gex + q * 1024;
      gq[(r0 + 0) * 16 + (l & 15)] = acc[m].x;
      gq[(r0 + 1) * 16 + (l & 15)] = acc[m].y;
      gq[(r0 + 2) * 16 + (l & 15)] = acc[m].z;
      gq[(r0 + 3) * 16 + (l & 15)] = acc[m].w;
    }
    __syncthreads();
    // activations; c stays in registers
    u16* hb = hbuf + ((size_t)(d * 2 + (t & 1)) * 64) * 512;
    #pragma unroll
    for (int p = 0; p < 4; p++) {
      int idx = tid + p * 256;
      int b = idx >> 4, hc = idx & 15;
      float gi = gex[0 * 1024 + b * 16 + hc];
      float gf = gex[1 * 1024 + b * 16 + hc];
      float gg = gex[2 * 1024 + b * 16 + hc];
      float go = gex[3 * 1024 + b * 16 + hc];
      float cn = sigm(gf) * c[p] + sigm(gi) * tanh_fast(gg);
      c[p] = cn;
      float hn = sigm(go) * tanh_fast(cn);
      u16 hv = f2b(hn);
      // chunk-swizzled broadcast buffer: byte ^= (b&7)<<4
      hb[b * 512 + ((((cg * 16 + hc) * 2) ^ ((b & 7) << 4)) >> 1)] = hv;
      h_all[((size_t)tau * 64 + b) * 1024 + d * 512 + cg * 16 + hc] = hv;
    }
    __threadfence();
    __syncthreads();
    if (t < 511) {
      // stage x(t+1) now — independent of the barrier, overlaps the spin
      int taun = d ? (511 - t - 1) : (t + 1);
      #pragma unroll
      for (int i = 0; i < 16; i++) {
        int r = q * 16 + i;
        const u16* src = embeds + ((size_t)(taun * 64 + r)) * 512 + (size_t)(l ^ (r & 7)) * 8;
        gload_lds16(src, x_lds + r * 512);
      }
      if (tid == 0) {   // per-direction monotonic-count barrier (32 WGs, all co-resident)
        __hip_atomic_fetch_add(&bar[d], 1, __ATOMIC_RELEASE, __HIP_MEMORY_SCOPE_AGENT);
        int target = 32 * (t + 1);
        long guard = 0;
        while (__hip_atomic_load(&bar[d], __ATOMIC_ACQUIRE, __HIP_MEMORY_SCOPE_AGENT) < target) {
          __builtin_amdgcn_s_sleep(2);
          if (++guard > (1L << 26)) break;   // anti-deadlock escape
        }
      }
      __syncthreads();
      __threadfence();                        // acquire: see other WGs' hbuf writes
      // stage h(t) from hbuf (already chunk-swizzled at write time)
      const u16* srcb = hbuf + ((size_t)(d * 2 + (t & 1)) * 64) * 512;
      #pragma unroll
      for (int i = 0; i < 16; i++) {
        int r = q * 16 + i;
        gload_lds16(srcb + r * 512 + l * 8, h_lds + r * 512);
      }
      __syncthreads();                        // drains x and h staging
    }
  }
}

// ---------- 5. feats = h_all @ w_tag^T + b_tag ----------
__launch_bounds__(256, 4)
__global__ void k_feats(const u16* __restrict__ h_all, const u16* __restrict__ wtf,
                        const float* __restrict__ btag, float* __restrict__ feats) {
  int Mt = blockIdx.x * 4 + (threadIdx.x >> 6);
  int l = threadIdx.x & 63;
  float bt = btag[l & 15];
  f32x4 acc; acc.x = bt; acc.y = bt; acc.z = bt; acc.w = bt;
  const u16* arow = h_all + ((size_t)Mt * 16 + (l & 15)) * 1024 + (l >> 4) * 8;
  #pragma unroll
  for (int kc = 0; kc < 32; kc++) {
    bf16x8 a = *(const bf16x8*)(arow + kc * 32);
    bf16x8 b = ((const bf16x8*)wtf)[kc * 64 + l];
    acc = __builtin_amdgcn_mfma_f32_16x16x32_bf16(a, b, acc, 0, 0, 0);
  }
  int r0 = (l >> 4) * 4;
  feats[((size_t)Mt * 16 + r0 + 0) * 16 + (l & 15)] = acc.x;
  feats[((size_t)Mt * 16 + r0 + 1) * 16 + (l & 15)] = acc.y;
  feats[((size_t)Mt * 16 + r0 + 2) * 16 + (l & 15)] = acc.z;
  feats[((size_t)Mt * 16 + r0 + 3) * 16 + (l & 15)] = acc.w;
}

// ---------- 6. CRF forward scan; one wave per batch ----------
__global__ void k_crf(const float* __restrict__ feats, const float* __restrict__ trans,
                      float* __restrict__ out) {
  int b = blockIdx.x;
  int l = threadIdx.x;
  int j = l & 15;
  float T[16];
  #pragma unroll
  for (int i = 0; i < 16; i++) T[i] = trans[j * 16 + i];
  float alpha = (j == 14) ? 0.f : -10000.f;   // START = 14
  for (int t = 0; t < 512; t++) {
    float feat = feats[((size_t)t * 64 + b) * 16 + j];
    float s[16];
    float m = -3.0e38f;
    #pragma unroll
    for (int i = 0; i < 16; i++) {
      float ai = __shfl(alpha, i, 16);
      s[i] = ai + T[i];
      m = fmaxf(m, s[i]);
    }
    float sum = 0.f;
    #pragma unroll
    for (int i = 0; i < 16; i++) sum += __expf(s[i] - m);
    alpha = m + __logf(sum) + feat;
  }
  float term = alpha + trans[15 * 16 + j];    // STOP = 15
  float m2 = term;
  #pragma unroll
  for (int o = 8; o >= 1; o >>= 1) m2 = fmaxf(m2, __shfl_xor(m2, o, 16));
  float e = __expf(term - m2);
  #pragma unroll
  for (int o = 8; o >= 1; o >>= 1) e += __shfl_xor(e, o, 16);
  if (l == 0) out[b] = m2 + __logf(e);
}

// ---------- launch ----------
extern "C" void kernel_launch(void* const* d_in, const int* in_sizes, int n_in,
                              void* d_out, int out_size, void* d_ws, size_t ws_size,
                              hipStream_t stream) {
  const int*   tokens = (const int*)d_in[0];
  const float* embed  = (const float*)d_in[1];
  const float* w_ih_f = (const float*)d_in[2];
  const float* w_hh_f = (const float*)d_in[3];
  const float* b_f    = (const float*)d_in[4];
  const float* w_ih_b = (const float*)d_in[5];
  const float* w_hh_b = (const float*)d_in[6];
  const float* b_b    = (const float*)d_in[7];
  const float* w_tag  = (const float*)d_in[8];
  const float* b_tag  = (const float*)d_in[9];
  const float* trans  = (const float*)d_in[10];
  float* out = (float*)d_out;

  // workspace plan: ~111 MB total (was 376 MB with the materialized ih-gate
  // buffer — prime suspect for the round-1 memory-fault abort)
  char* ws = (char*)d_ws;
  size_t off = 0;
  auto alloc = [&](size_t bytes) -> void* {
    void* p = ws + off;
    off = (off + bytes + 255) & ~(size_t)255;
    return p;
  };
  u16* embeds = (u16*)alloc(33554432);     // [32768][512] bf16
  u16* wih16  = (u16*)alloc(4194304);      // [2][2048][512] bf16
  u16* whh16  = (u16*)alloc(4194304);      // [2][2048][512] bf16
  u16* wtf    = (u16*)alloc(32768);        // packed w_tag frags
  u16* hbuf   = (u16*)alloc(262144);       // h ping-pong (2 dirs x 2 slots)
  u16* h_all  = (u16*)alloc(67108864);     // [512][64][1024] bf16
  float* feats = (float*)alloc(2097152);   // [512][64][16] f32
  int* bar    = (int*)alloc(256);

  hipMemsetAsync(bar, 0, 256, stream);
  k_cvt_bf16<<<512, 256, 0, stream>>>(w_ih_f, wih16,            131072);
  k_cvt_bf16<<<512, 256, 0, stream>>>(w_ih_b, wih16 + 1048576,  131072);
  k_cvt_bf16<<<512, 256, 0, stream>>>(w_hh_f, whh16,            131072);
  k_cvt_bf16<<<512, 256, 0, stream>>>(w_hh_b, whh16 + 1048576,  131072);
  k_embed<<<8192, 256, 0, stream>>>(tokens, embed, embeds);
  k_pack_wtag<<<1, 256, 0, stream>>>(w_tag, wtf);
  k_lstm<<<64, 256, 0, stream>>>(whh16, wih16, b_f, b_b, embeds, hbuf, h_all, bar);
  k_feats<<<512, 256, 0, stream>>>(h_all, wtf, b_tag, feats);
  k_crf<<<64, 64, 0, stream>>>(feats, trans, out);
}

// Round 5
// 2821.084 us; speedup vs baseline: 3.1493x; 3.1493x over previous
//
#include <hip/hip_runtime.h>

typedef __attribute__((ext_vector_type(8))) short bf16x8;
typedef __attribute__((ext_vector_type(4))) float f32x4;
typedef unsigned short u16;
typedef unsigned int u32;

#define AS1 __attribute__((address_space(1)))
#define AS3 __attribute__((address_space(3)))

// ---------- helpers ----------
__device__ __forceinline__ u16 f2b(float f) {
  union { float f; u32 i; } v; v.f = f;
  u32 u = v.i;
  return (u16)((u + 0x7FFFu + ((u >> 16) & 1u)) >> 16);   // RNE
}
__device__ __forceinline__ void gload_lds16(const void* g, void* lds) {
  __builtin_amdgcn_global_load_lds((const AS1 u32*)g, (AS3 u32*)lds, 16, 0, 0);
}
__device__ __forceinline__ float sigm(float x) { return 1.f / (1.f + __expf(-x)); }
__device__ __forceinline__ float tanh_fast(float x) { return 1.f - 2.f / (__expf(2.f * x) + 1.f); }

// device-coherent (PoC) accesses: sc0 sc1 bypass L1/L2 so cross-XCD data is
// seen without any cache flush/invalidate (the round-2 performance killer).
__device__ __forceinline__ void store_short_sc(u16* p, u32 v) {
  asm volatile("global_store_short %0, %1, off sc0 sc1" :: "v"(p), "v"(v) : "memory");
}
__device__ __forceinline__ uint4 load_b128_sc(const u16* p) {
  uint4 v;
  asm volatile("global_load_dwordx4 %0, %1, off sc0 sc1" : "=v"(v) : "v"(p) : "memory");
  return v;
}
__device__ __forceinline__ int load_i32_sc(const int* p) {
  int v;
  asm volatile("global_load_dword %0, %1, off sc0 sc1\n\ts_waitcnt vmcnt(0)"
               : "=v"(v) : "v"(p) : "memory");
  return v;
}

// ---------- 1. f32 -> bf16 convert (8 elems/thread) ----------
__global__ void k_cvt_bf16(const float* __restrict__ src, u16* __restrict__ dst, int n8) {
  int i = blockIdx.x * 256 + threadIdx.x;
  if (i < n8) {
    const float4* s = (const float4*)src + (size_t)i * 2;
    float4 a = s[0], b = s[1];
    u16 o[8] = { f2b(a.x), f2b(a.y), f2b(a.z), f2b(a.w), f2b(b.x), f2b(b.y), f2b(b.z), f2b(b.w) };
    *(uint4*)(dst + (size_t)i * 8) = *(uint4*)o;
  }
}

// ---------- 2. embedding lookup -> bf16 [32768][512] (row = t*64+b) ----------
__global__ void k_embed(const int* __restrict__ tokens, const float* __restrict__ embed,
                        u16* __restrict__ out) {
  int row = blockIdx.x * 4 + (threadIdx.x >> 6);
  int e0  = (threadIdx.x & 63) * 8;
  int tok = tokens[row];
  const float4* s = (const float4*)(embed + (size_t)tok * 512 + e0);
  float4 a = s[0], b = s[1];
  u16 o[8] = { f2b(a.x), f2b(a.y), f2b(a.z), f2b(a.w), f2b(b.x), f2b(b.y), f2b(b.z), f2b(b.w) };
  *(uint4*)(out + (size_t)row * 512 + e0) = *(uint4*)o;
}

// ---------- 3. pack w_tag [16][1024] f32 -> B-frag stream [32 kc][64 lane][8] bf16 ----------
__global__ void k_pack_wtag(const float* __restrict__ wtag, u16* __restrict__ out) {
  for (int s = threadIdx.x; s < 2048; s += 256) {
    int kc = s >> 6, lane = s & 63;
    int col = lane & 15, k0 = kc * 32 + (lane >> 4) * 8;
    const float4* src = (const float4*)(wtag + col * 1024 + k0);
    float4 a = src[0], b = src[1];
    u16 o[8] = { f2b(a.x), f2b(a.y), f2b(a.z), f2b(a.w), f2b(b.x), f2b(b.y), f2b(b.z), f2b(b.w) };
    *(uint4*)(out + (size_t)s * 8) = *(uint4*)o;
  }
}

// ---------- 4. persistent bi-LSTM recurrence (K-split across waves) ----------
// 64 WGs; slot = blockIdx.x (no placement assumptions -> deadlock-free).
// d = wg>>5, cg = wg&31 owns h-cols [cg*16, cg*16+16) of direction d.
// Wave q owns K-quarter q (128 of 512) for ALL 4 gates x ALL 4 M-tiles:
//   weights = 32 B-frags = 128 VGPR; acc[4 M][4 gates] partial sums;
//   cross-wave K-reduction through LDS (overlays h_lds, 2-way-swizzled).
__launch_bounds__(256, 1)
__global__ void k_lstm(const u16* __restrict__ whh,      // [2][2048][512] bf16 rm
                       const u16* __restrict__ wih,      // [2][2048][512] bf16 rm
                       const float* __restrict__ bias_f, const float* __restrict__ bias_b,
                       const u16* __restrict__ embeds,   // [512*64][512] bf16 rm
                       u16* __restrict__ hbuf,           // [2][4][64][512] bf16 plain
                       u16* __restrict__ h_all,          // [512][64][1024] bf16 rm
                       int* __restrict__ ctrl) {
  __shared__ u16 x_lds[64 * 512];          // 64 KB
  __shared__ u16 h_lds[64 * 512];          // 64 KB; reused as f32 partial buffer
  float* part = (float*)h_lds;             // [w:4][m:4][g:4][256] f32 (i^hi swizzle)
  int wg = blockIdx.x;
  int d = wg >> 5, cg = wg & 31;
  int tid = threadIdx.x, q = tid >> 6, l = tid & 63;
  int* bar = ctrl + d * 64;                // separate 256B line per direction

  // weight B-fragments, K-quarter q, all 4 gates: 128 VGPR total
  bf16x8 wreg[4][4], xreg[4][4];
  #pragma unroll
  for (int g = 0; g < 4; g++)
    #pragma unroll
    for (int kk = 0; kk < 4; kk++) {
      size_t off = ((size_t)d * 2048 + g * 512 + cg * 16 + (l & 15)) * 512
                 + (q * 4 + kk) * 32 + (l >> 4) * 8;
      wreg[g][kk] = *(const bf16x8*)(whh + off);
      xreg[g][kk] = *(const bf16x8*)(wih + off);
    }
  float bias[4];
  #pragma unroll
  for (int g = 0; g < 4; g++) bias[g] = (d ? bias_b : bias_f)[g * 512 + cg * 16 + (l & 15)];

  // zero h(-1)
  {
    uint4 z = {0, 0, 0, 0};
    for (int i = tid; i < 4096; i += 256) ((uint4*)h_lds)[i] = z;
  }
  float c[4] = {0.f, 0.f, 0.f, 0.f};

  // pre-stage x(tau0): pre-swizzled global source -> linear LDS (wave q: rows q*16..+15)
  {
    int tau0 = d ? 511 : 0;
    #pragma unroll
    for (int i = 0; i < 16; i++) {
      int r = q * 16 + i;
      gload_lds16(embeds + ((size_t)(tau0 * 64 + r)) * 512 + (size_t)(l ^ (r & 7)) * 8,
                  x_lds + r * 512);
    }
  }
  __syncthreads();

  for (int t = 0; t < 512; t++) {
    int tau = d ? (511 - t) : t;
    f32x4 acc[4][4] = {};                  // [m][g] partial over K-quarter q
    // ---- x-pass (h_lds staging from prev tail may still be in lgkm flight) ----
    #pragma unroll
    for (int kk = 0; kk < 4; kk++) {
      bf16x8 ax[4];
      #pragma unroll
      for (int m = 0; m < 4; m++) {
        int row = m * 16 + (l & 15);
        int u = ((q * 4 + kk) * 4 + (l >> 4)) ^ (row & 7);
        ax[m] = *(const bf16x8*)(x_lds + row * 512 + u * 8);
      }
      #pragma unroll
      for (int m = 0; m < 4; m++)
        #pragma unroll
        for (int g = 0; g < 4; g++)
          acc[m][g] = __builtin_amdgcn_mfma_f32_16x16x32_bf16(ax[m], xreg[g][kk], acc[m][g], 0, 0, 0);
    }
    __syncthreads();                       // S1: publish h_lds staging; x-reads done
    // ---- h-pass ----
    #pragma unroll
    for (int kk = 0; kk < 4; kk++) {
      bf16x8 ah[4];
      #pragma unroll
      for (int m = 0; m < 4; m++) {
        int row = m * 16 + (l & 15);
        int u = ((q * 4 + kk) * 4 + (l >> 4)) ^ (row & 7);
        ah[m] = *(const bf16x8*)(h_lds + row * 512 + u * 8);
      }
      #pragma unroll
      for (int m = 0; m < 4; m++)
        #pragma unroll
        for (int g = 0; g < 4; g++)
          acc[m][g] = __builtin_amdgcn_mfma_f32_16x16x32_bf16(ah[m], wreg[g][kk], acc[m][g], 0, 0, 0);
    }
    __syncthreads();                       // S2: h-reads done; h_lds free for partials
    // ---- write K-partials (C/D: col=l&15, row=(l>>4)*4+i; store at i^hi -> 2-way) ----
    {
      int hi = l >> 4, col = l & 15;
      #pragma unroll
      for (int m = 0; m < 4; m++)
        #pragma unroll
        for (int g = 0; g < 4; g++) {
          float* tp = part + ((q * 16 + m * 4 + g) << 8);
          #pragma unroll
          for (int i = 0; i < 4; i++)
            tp[hi * 64 + ((i ^ hi) & 3) * 16 + col] = acc[m][g][i];
        }
    }
    __syncthreads();                       // S3: partials visible
    // ---- gather 4-way K-reduction + activations (thread: pairs P=tid+p*256) ----
    u16* hb = hbuf + ((size_t)(d * 4 + (t & 3)) * 64) * 512;
    int i0 = l >> 4, col = l & 15;
    #pragma unroll
    for (int p = 0; p < 4; p++) {
      int b = (tid >> 4) + p * 16;         // batch row; m-tile = p, rrow hi = q
      float gv[4];
      #pragma unroll
      for (int g = 0; g < 4; g++) {
        float s = bias[g];
        #pragma unroll
        for (int w = 0; w < 4; w++)
          s += part[((w * 16 + p * 4 + g) << 8) + q * 64 + ((i0 ^ q) & 3) * 16 + col];
        gv[g] = s;
      }
      float cn = sigm(gv[1]) * c[p] + sigm(gv[0]) * tanh_fast(gv[2]);
      c[p] = cn;
      float hn = sigm(gv[3]) * tanh_fast(cn);
      u16 hv = f2b(hn);
      store_short_sc(hb + b * 512 + cg * 16 + col, (u32)hv);          // -> PoC (L3)
      h_all[((size_t)tau * 64 + b) * 1024 + d * 512 + cg * 16 + col] = hv;
    }
    if (t < 511) {
      __syncthreads();   // S4: per-wave vmcnt(0) before s_barrier => h stores at PoC
      if (tid == 0)      // arrive (relaxed RMW at L3; no cache side-effects)
        __hip_atomic_fetch_add(bar, 1, __ATOMIC_RELAXED, __HIP_MEMORY_SCOPE_AGENT);
      // stage x(t+1) — overlaps the spin
      int taun = d ? (510 - t) : (t + 1);
      #pragma unroll
      for (int i = 0; i < 16; i++) {
        int r = q * 16 + i;
        gload_lds16(embeds + ((size_t)(taun * 64 + r)) * 512 + (size_t)(l ^ (r & 7)) * 8,
                    x_lds + r * 512);
      }
      if (tid == 0) {    // poll with plain sc0sc1 load (no atomic-ALU serialization)
        int target = 32 * (t + 1);
        int guard = 0;
        while (load_i32_sc(bar) < target) {
          __builtin_amdgcn_s_sleep(2);
          if (++guard > (1 << 16)) break;  // insurance: wrong-fast beats hang
        }
      }
      __syncthreads();   // S5: release; waves 1-3 drained their x-stage at barrier
      // stage h(t): wave q stages rows q*16..+15; full 1KB row per instruction,
      // coalesced PoC read + XOR-swizzled ds_write (published by next S1)
      const u16* hsrc = hbuf + ((size_t)(d * 4 + (t & 3)) * 64) * 512;
      uint4 hld[8];
      #pragma unroll
      for (int i = 0; i < 8; i++)
        hld[i] = load_b128_sc(hsrc + (size_t)(q * 16 + i) * 512 + l * 8);
      asm volatile("s_waitcnt vmcnt(0)" ::: "memory");
      #pragma unroll
      for (int i = 0; i < 8; i++) {
        int r = q * 16 + i;
        *(uint4*)(h_lds + r * 512 + (size_t)(l ^ (r & 7)) * 8) = hld[i];
      }
      #pragma unroll
      for (int i = 8; i < 16; i++)
        hld[i - 8] = load_b128_sc(hsrc + (size_t)(q * 16 + i) * 512 + l * 8);
      asm volatile("s_waitcnt vmcnt(0)" ::: "memory");
      #pragma unroll
      for (int i = 8; i < 16; i++) {
        int r = q * 16 + i;
        *(uint4*)(h_lds + r * 512 + (size_t)(l ^ (r & 7)) * 8) = hld[i - 8];
      }
    }
  }
}

// ---------- 5. feats = h_all @ w_tag^T + b_tag ----------
__launch_bounds__(256, 4)
__global__ void k_feats(const u16* __restrict__ h_all, const u16* __restrict__ wtf,
                        const float* __restrict__ btag, float* __restrict__ feats) {
  int Mt = blockIdx.x * 4 + (threadIdx.x >> 6);
  int l = threadIdx.x & 63;
  float bt = btag[l & 15];
  f32x4 acc; acc.x = bt; acc.y = bt; acc.z = bt; acc.w = bt;
  const u16* arow = h_all + ((size_t)Mt * 16 + (l & 15)) * 1024 + (l >> 4) * 8;
  #pragma unroll
  for (int kc = 0; kc < 32; kc++) {
    bf16x8 a = *(const bf16x8*)(arow + kc * 32);
    bf16x8 b = ((const bf16x8*)wtf)[kc * 64 + l];
    acc = __builtin_amdgcn_mfma_f32_16x16x32_bf16(a, b, acc, 0, 0, 0);
  }
  int r0 = (l >> 4) * 4;
  feats[((size_t)Mt * 16 + r0 + 0) * 16 + (l & 15)] = acc.x;
  feats[((size_t)Mt * 16 + r0 + 1) * 16 + (l & 15)] = acc.y;
  feats[((size_t)Mt * 16 + r0 + 2) * 16 + (l & 15)] = acc.z;
  feats[((size_t)Mt * 16 + r0 + 3) * 16 + (l & 15)] = acc.w;
}

// ---------- 6. CRF forward scan; one wave per batch ----------
__global__ void k_crf(const float* __restrict__ feats, const float* __restrict__ trans,
                      float* __restrict__ out) {
  int b = blockIdx.x;
  int l = threadIdx.x;
  int j = l & 15;
  float T[16];
  #pragma unroll
  for (int i = 0; i < 16; i++) T[i] = trans[j * 16 + i];
  float alpha = (j == 14) ? 0.f : -10000.f;   // START = 14
  for (int t = 0; t < 512; t++) {
    float feat = feats[((size_t)t * 64 + b) * 16 + j];
    float s[16];
    float m = -3.0e38f;
    #pragma unroll
    for (int i = 0; i < 16; i++) {
      float ai = __shfl(alpha, i, 16);
      s[i] = ai + T[i];
      m = fmaxf(m, s[i]);
    }
    float sum = 0.f;
    #pragma unroll
    for (int i = 0; i < 16; i++) sum += __expf(s[i] - m);
    alpha = m + __logf(sum) + feat;
  }
  float term = alpha + trans[15 * 16 + j];    // STOP = 15
  float m2 = term;
  #pragma unroll
  for (int o = 8; o >= 1; o >>= 1) m2 = fmaxf(m2, __shfl_xor(m2, o, 16));
  float e = __expf(term - m2);
  #pragma unroll
  for (int o = 8; o >= 1; o >>= 1) e += __shfl_xor(e, o, 16);
  if (l == 0) out[b] = m2 + __logf(e);
}

// ---------- launch ----------
extern "C" void kernel_launch(void* const* d_in, const int* in_sizes, int n_in,
                              void* d_out, int out_size, void* d_ws, size_t ws_size,
                              hipStream_t stream) {
  const int*   tokens = (const int*)d_in[0];
  const float* embed  = (const float*)d_in[1];
  const float* w_ih_f = (const float*)d_in[2];
  const float* w_hh_f = (const float*)d_in[3];
  const float* b_f    = (const float*)d_in[4];
  const float* w_ih_b = (const float*)d_in[5];
  const float* w_hh_b = (const float*)d_in[6];
  const float* b_b    = (const float*)d_in[7];
  const float* w_tag  = (const float*)d_in[8];
  const float* b_tag  = (const float*)d_in[9];
  const float* trans  = (const float*)d_in[10];
  float* out = (float*)d_out;

  char* ws = (char*)d_ws;
  size_t off = 0;
  auto alloc = [&](size_t bytes) -> void* {
    void* p = ws + off;
    off = (off + bytes + 255) & ~(size_t)255;
    return p;
  };
  u16* embeds = (u16*)alloc(33554432);     // [32768][512] bf16
  u16* wih16  = (u16*)alloc(4194304);      // [2][2048][512] bf16
  u16* whh16  = (u16*)alloc(4194304);      // [2][2048][512] bf16
  u16* wtf    = (u16*)alloc(32768);        // packed w_tag frags
  u16* hbuf   = (u16*)alloc(524288);       // h ring (2 dirs x 4 slots), plain layout
  u16* h_all  = (u16*)alloc(67108864);     // [512][64][1024] bf16
  float* feats = (float*)alloc(2097152);   // [512][64][16] f32
  int* ctrl   = (int*)alloc(4096);         // per-direction barrier counters

  hipMemsetAsync(ctrl, 0, 4096, stream);
  k_cvt_bf16<<<512, 256, 0, stream>>>(w_ih_f, wih16,            131072);
  k_cvt_bf16<<<512, 256, 0, stream>>>(w_ih_b, wih16 + 1048576,  131072);
  k_cvt_bf16<<<512, 256, 0, stream>>>(w_hh_f, whh16,            131072);
  k_cvt_bf16<<<512, 256, 0, stream>>>(w_hh_b, whh16 + 1048576,  131072);
  k_embed<<<8192, 256, 0, stream>>>(tokens, embed, embeds);
  k_pack_wtag<<<1, 256, 0, stream>>>(w_tag, wtf);
  k_lstm<<<64, 256, 0, stream>>>(whh16, wih16, b_f, b_b, embeds, hbuf, h_all, ctrl);
  k_feats<<<512, 256, 0, stream>>>(h_all, wtf, b_tag, feats);
  k_crf<<<64, 64, 0, stream>>>(feats, trans, out);
}